// Round 1
// baseline (65363.904 us; speedup 1.0000x reference)
//
#include <hip/hip_runtime.h>
#include <cstdint>
#include <cstddef>

#define HS 512
#define INW 2048
#define MBK 100

constexpr int TPB   = 256;
constexpr int GBLK  = 128;
constexpr int NWAVE = GBLK * (TPB / 64);   // 512 waves
constexpr int SUBC  = 16;                  // barrier sub-counters
constexpr int SUBN  = GBLK / SUBC;         // 8 blocks per sub-counter

// ---------------- workspace layout (float offsets) ----------------
constexpr size_t SZ_TWrp  = 100*1536;
constexpr size_t SZ_TWwp  = 3*1536;
constexpr size_t SZ_TWwpx = 100*512;
constexpr size_t SZ_TWc   = 512*512;
constexpr size_t SZ_TWr   = 512*1024;
constexpr size_t SZ_P512  = 4096*512;
constexpr size_t SZ_P100  = 4096*100;

constexpr size_t OFF_TWrp  = 0;
constexpr size_t OFF_TWwp  = OFF_TWrp  + SZ_TWrp;
constexpr size_t OFF_TWwpa = OFF_TWwp  + SZ_TWwp;
constexpr size_t OFF_TWwpm = OFF_TWwpa + SZ_TWwpx;
constexpr size_t OFF_TWca  = OFF_TWwpm + SZ_TWwpx;
constexpr size_t OFF_TWcm  = OFF_TWca  + SZ_TWc;
constexpr size_t OFF_TWrh  = OFF_TWcm  + SZ_TWc;
constexpr size_t OFF_TWrha = OFF_TWrh  + SZ_TWr;
constexpr size_t OFF_TWrhm = OFF_TWrha + SZ_TWr;
constexpr size_t OFF_PAca  = OFF_TWrhm + SZ_TWr;
constexpr size_t OFF_PMcm  = OFF_PAca  + SZ_P512;
constexpr size_t OFF_PArha = OFF_PMcm  + SZ_P512;
constexpr size_t OFF_PMrhm = OFF_PArha + SZ_P512;
constexpr size_t OFF_PAwpa = OFF_PMrhm + SZ_P512;
constexpr size_t OFF_PMwpm = OFF_PAwpa + SZ_P100;
constexpr size_t OFF_STATE = OFF_PMwpm + SZ_P100;

// state sub-offsets (floats, relative to STATE)
constexpr size_t ST_CARRY = 0;                    // 2 x 1536 (ping-pong, layout [ha|hm|h])
constexpr size_t ST_CA    = 3072;                 // 512
constexpr size_t ST_CM    = 3584;                 // 512
constexpr size_t ST_GRP   = 4096;                 // 128 (rp logits)
constexpr size_t ST_GWP   = 4224;                 // 32  (wp logits)
constexpr size_t ST_GWPA  = 4256;                 // 128
constexpr size_t ST_GWPM  = 4384;                 // 128
constexpr size_t ST_R     = 4512;                 // 512
constexpr size_t ST_MEMT  = 5024;                 // 512*100 (mem transposed [HS][MB])
constexpr size_t ST_BARS  = ST_MEMT + 512*100;    // 56224; 1024 floats used as uints
constexpr size_t ST_TOTAL = ST_BARS + 1024;       // 57248 floats

// ---------------- device helpers ----------------
__device__ __forceinline__ float gld(const float* p) {
  return __hip_atomic_load(const_cast<float*>(p), __ATOMIC_RELAXED, __HIP_MEMORY_SCOPE_AGENT);
}
__device__ __forceinline__ void gst(float* p, float v) {
  __hip_atomic_store(p, v, __ATOMIC_RELAXED, __HIP_MEMORY_SCOPE_AGENT);
}
__device__ __forceinline__ float wredsum(float v) {
  #pragma unroll
  for (int o = 32; o; o >>= 1) v += __shfl_down(v, o, 64);
  return v;  // valid on lane 0
}

// lean monotonic grid barrier: no resets, no acquire/release cache maintenance.
// Cross-block data goes through sc1 (agent-scope relaxed) atomics, so the only
// requirement is store-completion before arrival; __syncthreads drains vmcnt.
__device__ __forceinline__ void gbar(unsigned* bars, unsigned n) {
  __syncthreads();  // emits s_waitcnt vmcnt(0) lgkmcnt(0) + s_barrier
  if (threadIdx.x == 0) {
    unsigned sub = (unsigned)blockIdx.x & (SUBC - 1);
    unsigned p = __hip_atomic_fetch_add(bars + sub*32, 1u, __ATOMIC_RELAXED, __HIP_MEMORY_SCOPE_AGENT);
    if (p == (unsigned)SUBN * n - 1u) {
      unsigned q = __hip_atomic_fetch_add(bars + SUBC*32, 1u, __ATOMIC_RELAXED, __HIP_MEMORY_SCOPE_AGENT);
      if (q == (unsigned)SUBC * n - 1u) {
        __hip_atomic_store(bars + SUBC*32 + 32, n, __ATOMIC_RELAXED, __HIP_MEMORY_SCOPE_AGENT);
      }
    }
    while (__hip_atomic_load(bars + SUBC*32 + 32, __ATOMIC_RELAXED, __HIP_MEMORY_SCOPE_AGENT) < n) { }
    __asm__ __volatile__("" ::: "memory");
  }
  __syncthreads();
}

// wave dot: w row (global, contiguous) x LDS vector, K = 256*k4 floats
__device__ __forceinline__ float dotK(const float* __restrict__ w, const float* x_lds, int k4) {
  int l = threadIdx.x & 63;
  const float4* w4 = (const float4*)w;
  const float4* x4 = (const float4*)x_lds;
  float acc = 0.f;
  #pragma unroll
  for (int it = 0; it < 6; ++it) {
    if (it >= k4) break;
    float4 a = w4[l + 64*it];
    float4 b = x4[l + 64*it];
    acc += a.x*b.x + a.y*b.y + a.z*b.z + a.w*b.w;
  }
  return acc;
}

__device__ __forceinline__ void softmax100(const float* g, float* s) {
  int l = threadIdx.x & 63;
  float x1 = (l < 100)      ? gld(g + l)      : -3.0e38f;
  float x2 = (l + 64 < 100) ? gld(g + l + 64) : -3.0e38f;
  float m = fmaxf(x1, x2);
  #pragma unroll
  for (int o = 32; o; o >>= 1) m = fmaxf(m, __shfl_xor(m, o, 64));
  float e1 = (l < 100) ? expf(x1 - m) : 0.f;
  float e2 = (l < 36)  ? expf(x2 - m) : 0.f;
  float ss = e1 + e2;
  #pragma unroll
  for (int o = 32; o; o >>= 1) ss += __shfl_xor(ss, o, 64);
  float inv = 1.f / ss;
  if (l < 100) s[l] = e1 * inv;
  if (l < 36)  s[l + 64] = e2 * inv;
}

__device__ __forceinline__ void softmax3(const float* g, float* s) {
  int l = threadIdx.x & 63;
  float x = (l < 3) ? gld(g + l) : -3.0e38f;
  float m = x;
  #pragma unroll
  for (int o = 32; o; o >>= 1) m = fmaxf(m, __shfl_xor(m, o, 64));
  float e = (l < 3) ? expf(x - m) : 0.f;
  float ss = e;
  #pragma unroll
  for (int o = 32; o; o >>= 1) ss += __shfl_xor(ss, o, 64);
  if (l < 3) s[l] = e / ss;
}

// ---------------- small prep kernels ----------------
__global__ void zeroK(float* p, int n) {
  int i = blockIdx.x * blockDim.x + threadIdx.x;
  int stride = gridDim.x * blockDim.x;
  for (; i < n; i += stride) p[i] = 0.f;
}

// dst[C][R] = src[R][C]^T   (tiled)
__global__ void transK(const float* __restrict__ src, float* __restrict__ dst, int R, int C) {
  __shared__ float tile[32][33];
  int c0 = blockIdx.x * 32, r0 = blockIdx.y * 32;
  for (int i = threadIdx.y; i < 32; i += 8) {
    int r = r0 + i, c = c0 + threadIdx.x;
    tile[i][threadIdx.x] = (r < R && c < C) ? src[(size_t)r * C + c] : 0.f;
  }
  __syncthreads();
  for (int i = threadIdx.y; i < 32; i += 8) {
    int c = c0 + i, r = r0 + threadIdx.x;
    if (c < C && r < R) dst[(size_t)c * R + r] = tile[threadIdx.x][i];
  }
}

// C[T,N] = X[T,2048] @ W[2048,N]   fp32, 64x64 tile, 256 threads, 4x4 micro
__global__ __launch_bounds__(256) void gemmK(const float* __restrict__ X,
                                             const float* __restrict__ W,
                                             float* __restrict__ C, int N) {
  __shared__ float As[16][68];  // [k][t]
  __shared__ float Bs[16][68];  // [k][n]
  int t0 = blockIdx.y * 64, n0 = blockIdx.x * 64;
  int tid = threadIdx.x;
  int tx = tid & 15, ty = tid >> 4;
  float acc[4][4] = {};
  for (int k0 = 0; k0 < 2048; k0 += 16) {
    {  // A: rows t0..t0+63, k k0..k0+15
      int r = tid >> 2, c = (tid & 3) * 4;
      float4 v = *(const float4*)(X + (size_t)(t0 + r) * 2048 + k0 + c);
      As[c + 0][r] = v.x; As[c + 1][r] = v.y; As[c + 2][r] = v.z; As[c + 3][r] = v.w;
    }
    {  // B: rows k0..k0+15, cols n0..n0+63
      int kr = tid >> 4, c = (tid & 15) * 4;
      int gcol = n0 + c;
      const float* src = W + (size_t)(k0 + kr) * N + gcol;
      if (gcol + 3 < N) {
        float4 v = *(const float4*)src;
        Bs[kr][c] = v.x; Bs[kr][c + 1] = v.y; Bs[kr][c + 2] = v.z; Bs[kr][c + 3] = v.w;
      } else {
        #pragma unroll
        for (int i = 0; i < 4; ++i) Bs[kr][c + i] = (gcol + i < N) ? src[i] : 0.f;
      }
    }
    __syncthreads();
    #pragma unroll
    for (int kk = 0; kk < 16; ++kk) {
      float4 a4 = *(const float4*)&As[kk][ty * 4];
      float4 b4 = *(const float4*)&Bs[kk][tx * 4];
      float av[4] = {a4.x, a4.y, a4.z, a4.w};
      float bv[4] = {b4.x, b4.y, b4.z, b4.w};
      #pragma unroll
      for (int i = 0; i < 4; ++i)
        #pragma unroll
        for (int j = 0; j < 4; ++j) acc[i][j] += av[i] * bv[j];
    }
    __syncthreads();
  }
  #pragma unroll
  for (int i = 0; i < 4; ++i)
    #pragma unroll
    for (int j = 0; j < 4; ++j) {
      int col = n0 + tx * 4 + j;
      if (col < N) C[(size_t)(t0 + ty * 4 + i) * N + col] = acc[i][j];
    }
}

// ---------------- persistent recurrence kernel ----------------
struct RArgs {
  const float *TWrp, *TWwp, *TWwpa, *TWwpm, *TWca, *TWcm, *TWrh, *TWrha, *TWrhm;
  const float *PAca, *PMcm, *PArha, *PMrhm, *PAwpa, *PMwpm;
  const float *b_ca, *b_cm, *b_wp, *b_wpa, *b_wpm, *b_rp, *b_rh, *b_rha, *b_rhm;
  float *carry, *ca, *cm, *grp, *gwp, *gwpa, *gwpm, *rbuf, *memT;
  unsigned *bars;
  float *out;
  int nT;
};

__global__ __launch_bounds__(TPB) void recurK(RArgs a) {
  const int lane = threadIdx.x & 63;
  const int wid  = threadIdx.x >> 6;
  const int gw   = blockIdx.x * (TPB / 64) + wid;

  __shared__ __align__(16) float s_x[2048];
  __shared__ float s_ar[100], s_awa[100], s_awm[100], s_aw[4];

  unsigned nb = 0;

  for (int t = 0; t < a.nT; ++t) {
    const float* carO = a.carry + (size_t)(t & 1) * 1536;
    float*       carN = a.carry + (size_t)((t + 1) & 1) * 1536;

    // ---------- Phase 1: carry matvecs (gates + content) ----------
    for (int i = threadIdx.x; i < 1536; i += TPB) s_x[i] = gld(carO + i);
    __syncthreads();

    for (int job = gw; job < 1327; job += NWAVE) {
      if (job < 100) {
        float v = wredsum(dotK(a.TWrp + (size_t)job * 1536, s_x, 6));
        if (!lane) gst(a.grp + job, v + a.b_rp[job]);
      } else if (job < 103) {
        int c = job - 100;
        float v = wredsum(dotK(a.TWwp + (size_t)c * 1536, s_x, 6));
        if (!lane) gst(a.gwp + c, v + a.b_wp[c]);
      } else if (job < 203) {
        int c = job - 103;
        float v = wredsum(dotK(a.TWwpa + (size_t)c * 512, s_x, 2));
        if (!lane) gst(a.gwpa + c, v + a.PAwpa[(size_t)t * 100 + c] + a.b_wpa[c]);
      } else if (job < 303) {
        int c = job - 203;
        float v = wredsum(dotK(a.TWwpm + (size_t)c * 512, s_x + 512, 2));
        if (!lane) gst(a.gwpm + c, v + a.PMwpm[(size_t)t * 100 + c] + a.b_wpm[c]);
      } else if (job < 815) {
        int c = job - 303;
        float v = wredsum(dotK(a.TWca + (size_t)c * 512, s_x, 2));
        if (!lane) gst(a.ca + c, fmaxf(v + a.PAca[(size_t)t * 512 + c] + a.b_ca[c], 0.f));
      } else {
        int c = job - 815;
        float v = wredsum(dotK(a.TWcm + (size_t)c * 512, s_x + 512, 2));
        if (!lane) gst(a.cm + c, fmaxf(v + a.PMcm[(size_t)t * 512 + c] + a.b_cm[c], 0.f));
      }
    }
    gbar(a.bars, ++nb);

    // ---------- Phase 2: softmaxes, r = ar@mem, mem update ----------
    if      (wid == 0) softmax100(a.grp,  s_ar);
    else if (wid == 1) softmax100(a.gwpa, s_awa);
    else if (wid == 2) softmax100(a.gwpm, s_awm);
    else               softmax3  (a.gwp,  s_aw);
    __syncthreads();
    {
      float aw0 = s_aw[0], aw1 = s_aw[1], aw2 = s_aw[2];
      for (int j = gw; j < HS; j += NWAVE) {   // NWAVE==512: one row per wave
        float caj = gld(a.ca + j), cmj = gld(a.cm + j);
        float* row = a.memT + (size_t)j * MBK;  // block-private: plain access
        float p = 0.f;
        if (lane < 100) {
          float v = row[lane];
          p += s_ar[lane] * v;
          row[lane] = aw0 * v + aw1 * s_awa[lane] * caj + aw2 * s_awm[lane] * cmj;
        }
        if (lane < 36) {
          int i = lane + 64;
          float v = row[i];
          p += s_ar[i] * v;
          row[i] = aw0 * v + aw1 * s_awa[i] * caj + aw2 * s_awm[i] * cmj;
        }
        p = wredsum(p);
        if (!lane) gst(a.rbuf + j, p);
      }
    }
    gbar(a.bars, ++nb);

    // ---------- Phase 3: hidden-state matvecs ----------
    for (int i = threadIdx.x; i < 512;  i += TPB) s_x[i]       = gld(a.rbuf + i);
    for (int i = threadIdx.x; i < 1536; i += TPB) s_x[512 + i] = gld(carO + i);
    __syncthreads();

    for (int job = gw; job < 1536; job += NWAVE) {
      int c = job & 511;
      int typ = job >> 9;  // 0:h1  1:ha1  2:hm1
      const float* w; int xo2;
      if      (typ == 0) { w = a.TWrh  + (size_t)c * 1024; xo2 = 512 + 1024; }  // h
      else if (typ == 1) { w = a.TWrha + (size_t)c * 1024; xo2 = 512 + 0;    }  // ha
      else               { w = a.TWrhm + (size_t)c * 1024; xo2 = 512 + 512;  }  // hm
      float v = dotK(w, s_x, 2) + dotK(w + 512, s_x + xo2, 2);
      v = wredsum(v);
      if (!lane) {
        if (typ == 0) {
          float h = fmaxf(v + a.b_rh[c], 0.f);
          a.out[(size_t)t * 512 + c] = h;       // plain; host reads after kernel end
          gst(carN + 1024 + c, h);
        } else if (typ == 1) {
          float h = fmaxf(v + a.PArha[(size_t)t * 512 + c] + a.b_rha[c], 0.f);
          gst(carN + c, h);
        } else {
          float h = fmaxf(v + a.PMrhm[(size_t)t * 512 + c] + a.b_rhm[c], 0.f);
          gst(carN + 512 + c, h);
        }
      }
    }
    gbar(a.bars, ++nb);
  }
}

// ---------------- host ----------------
extern "C" void kernel_launch(void* const* d_in, const int* in_sizes, int n_in,
                              void* d_out, int out_size, void* d_ws, size_t ws_size,
                              hipStream_t stream) {
  const float* Xa    = (const float*)d_in[0];
  const float* Xm    = (const float*)d_in[1];
  const float* W_ca  = (const float*)d_in[2];  const float* b_ca  = (const float*)d_in[3];
  const float* W_cm  = (const float*)d_in[4];  const float* b_cm  = (const float*)d_in[5];
  const float* W_wp  = (const float*)d_in[6];  const float* b_wp  = (const float*)d_in[7];
  const float* W_wpa = (const float*)d_in[8];  const float* b_wpa = (const float*)d_in[9];
  const float* W_wpm = (const float*)d_in[10]; const float* b_wpm = (const float*)d_in[11];
  const float* W_rp  = (const float*)d_in[12]; const float* b_rp  = (const float*)d_in[13];
  const float* W_rh  = (const float*)d_in[14]; const float* b_rh  = (const float*)d_in[15];
  const float* W_rha = (const float*)d_in[16]; const float* b_rha = (const float*)d_in[17];
  const float* W_rhm = (const float*)d_in[18]; const float* b_rhm = (const float*)d_in[19];

  int nT = out_size / HS;   // 4096
  float* ws = (float*)d_ws;
  float* state = ws + OFF_STATE;

  // zero recurrent state + barrier counters (ws is poisoned 0xAA before every call)
  zeroK<<<dim3(256), dim3(256), 0, stream>>>(state, (int)ST_TOTAL);

  // weight transposes (row-per-output-column layout for coalesced wave dots)
  dim3 tb(32, 8);
  auto tg = [](int R, int C) { return dim3((C + 31) / 32, (R + 31) / 32); };
  transK<<<tg(1536, 100), tb, 0, stream>>>(W_rp,               ws + OFF_TWrp,  1536, 100);
  transK<<<tg(1536, 3),   tb, 0, stream>>>(W_wp,               ws + OFF_TWwp,  1536, 3);
  transK<<<tg(512, 100),  tb, 0, stream>>>(W_wpa,              ws + OFF_TWwpa, 512, 100);
  transK<<<tg(512, 100),  tb, 0, stream>>>(W_wpm,              ws + OFF_TWwpm, 512, 100);
  transK<<<tg(512, 512),  tb, 0, stream>>>(W_ca,               ws + OFF_TWca,  512, 512);
  transK<<<tg(512, 512),  tb, 0, stream>>>(W_cm,               ws + OFF_TWcm,  512, 512);
  transK<<<tg(1024, 512), tb, 0, stream>>>(W_rh,               ws + OFF_TWrh,  1024, 512);
  transK<<<tg(1024, 512), tb, 0, stream>>>(W_rha + 2048 * 512, ws + OFF_TWrha, 1024, 512);
  transK<<<tg(1024, 512), tb, 0, stream>>>(W_rhm + 2048 * 512, ws + OFF_TWrhm, 1024, 512);

  // input-side GEMM precompute
  int tBlocks = nT / 64;
  gemmK<<<dim3(8, tBlocks), dim3(256), 0, stream>>>(Xa, W_ca  + 512 * 512, ws + OFF_PAca,  512);
  gemmK<<<dim3(8, tBlocks), dim3(256), 0, stream>>>(Xm, W_cm  + 512 * 512, ws + OFF_PMcm,  512);
  gemmK<<<dim3(8, tBlocks), dim3(256), 0, stream>>>(Xa, W_rha,             ws + OFF_PArha, 512);
  gemmK<<<dim3(8, tBlocks), dim3(256), 0, stream>>>(Xm, W_rhm,             ws + OFF_PMrhm, 512);
  gemmK<<<dim3(2, tBlocks), dim3(256), 0, stream>>>(Xa, W_wpa + 512 * 100, ws + OFF_PAwpa, 100);
  gemmK<<<dim3(2, tBlocks), dim3(256), 0, stream>>>(Xm, W_wpm + 512 * 100, ws + OFF_PMwpm, 100);

  // persistent recurrence
  RArgs a;
  a.TWrp  = ws + OFF_TWrp;  a.TWwp  = ws + OFF_TWwp;
  a.TWwpa = ws + OFF_TWwpa; a.TWwpm = ws + OFF_TWwpm;
  a.TWca  = ws + OFF_TWca;  a.TWcm  = ws + OFF_TWcm;
  a.TWrh  = ws + OFF_TWrh;  a.TWrha = ws + OFF_TWrha; a.TWrhm = ws + OFF_TWrhm;
  a.PAca  = ws + OFF_PAca;  a.PMcm  = ws + OFF_PMcm;
  a.PArha = ws + OFF_PArha; a.PMrhm = ws + OFF_PMrhm;
  a.PAwpa = ws + OFF_PAwpa; a.PMwpm = ws + OFF_PMwpm;
  a.b_ca = b_ca; a.b_cm = b_cm; a.b_wp = b_wp; a.b_wpa = b_wpa; a.b_wpm = b_wpm;
  a.b_rp = b_rp; a.b_rh = b_rh; a.b_rha = b_rha; a.b_rhm = b_rhm;
  a.carry = state + ST_CARRY;
  a.ca    = state + ST_CA;   a.cm   = state + ST_CM;
  a.grp   = state + ST_GRP;  a.gwp  = state + ST_GWP;
  a.gwpa  = state + ST_GWPA; a.gwpm = state + ST_GWPM;
  a.rbuf  = state + ST_R;    a.memT = state + ST_MEMT;
  a.bars  = (unsigned*)(state + ST_BARS);
  a.out   = (float*)d_out;
  a.nT    = nT;

  recurK<<<dim3(GBLK), dim3(TPB), 0, stream>>>(a);
}

// Round 2
// 46276.584 us; speedup vs baseline: 1.4125x; 1.4125x over previous
//
#include <hip/hip_runtime.h>
#include <cstdint>
#include <cstddef>

#define HS 512
#define MBK 100

constexpr int TPB   = 512;                 // 8 waves/block
constexpr int GBLK  = 64;
constexpr int NWAVE = GBLK * (TPB / 64);   // 512 waves
constexpr int OWNB  = 1536 / GBLK;         // 24 owned jobs per block

// ---------------- workspace layout (float offsets) ----------------
constexpr size_t OFF_TWrp  = 0;                       // [100][1536]
constexpr size_t OFF_TWwp  = OFF_TWrp  + 100*1536;    // [3][1536]
constexpr size_t OFF_TWwpa = OFF_TWwp  + 3*1536;      // [100][512]
constexpr size_t OFF_TWwpm = OFF_TWwpa + 100*512;
constexpr size_t OFF_TWca  = OFF_TWwpm + 100*512;     // [512][512]
constexpr size_t OFF_TWcm  = OFF_TWca  + 512*512;
constexpr size_t OFF_TWh0  = OFF_TWcm  + 512*512;     // W_rh[512:1024]^T  (h-part)
constexpr size_t OFF_TWh1  = OFF_TWh0  + 512*512;     // W_rha[2560:3072]^T (ha-part)
constexpr size_t OFF_TWh2  = OFF_TWh1  + 512*512;     // W_rhm[2560:3072]^T (hm-part)
constexpr size_t OFF_TWu0  = OFF_TWh2  + 512*512;     // W_rh[0:512]^T     (r-part)
constexpr size_t OFF_TWu1  = OFF_TWu0  + 512*512;     // W_rha[2048:2560]^T
constexpr size_t OFF_TWu2  = OFF_TWu1  + 512*512;     // W_rhm[2048:2560]^T
constexpr size_t OFF_PAca  = OFF_TWu2  + 512*512;     // [4096][512]
constexpr size_t OFF_PMcm  = OFF_PAca  + 4096*512;
constexpr size_t OFF_PArha = OFF_PMcm  + 4096*512;
constexpr size_t OFF_PMrhm = OFF_PArha + 4096*512;
constexpr size_t OFF_PAwpa = OFF_PMrhm + 4096*512;    // [4096][100]
constexpr size_t OFF_PMwpm = OFF_PAwpa + 4096*100;
constexpr size_t OFF_G     = OFF_PMwpm + 4096*100;    // [1536][128] rows head*512+j
constexpr size_t OFF_CARRY = OFF_G     + 1536*128;    // u64[2][1536] tagged
constexpr size_t OFF_BCAST = OFF_CARRY + 2*1536*2;    // u64[2][1344] tagged
// bcast layout: [0:512) ca  [512:1024) cm  [1024:1124) grp
//               [1124:1224) gwpa  [1224:1324) gwpm  [1324:1327) gwp

// ---------------- device helpers ----------------
__device__ __forceinline__ unsigned long long ald(const unsigned long long* p) {
  return __hip_atomic_load(const_cast<unsigned long long*>(p),
                           __ATOMIC_RELAXED, __HIP_MEMORY_SCOPE_AGENT);
}
__device__ __forceinline__ void gstTag(unsigned long long* p, float v, unsigned tag) {
  unsigned long long u = ((unsigned long long)tag << 32) | (unsigned long long)__float_as_uint(v);
  __hip_atomic_store(p, u, __ATOMIC_RELAXED, __HIP_MEMORY_SCOPE_AGENT);
}
__device__ __forceinline__ float xrsum(float v) {   // butterfly: all lanes get sum
  #pragma unroll
  for (int o = 32; o; o >>= 1) v += __shfl_xor(v, o, 64);
  return v;
}

template<int K4>
__device__ __forceinline__ float dotK(const float* __restrict__ w, const float* x_lds) {
  int l = threadIdx.x & 63;
  const float4* w4 = (const float4*)w;
  const float4* x4 = (const float4*)x_lds;
  float acc = 0.f;
  #pragma unroll
  for (int it = 0; it < K4; ++it) {
    float4 a = w4[l + 64*it];
    float4 b = x4[l + 64*it];
    acc += a.x*b.x + a.y*b.y + a.z*b.z + a.w*b.w;
  }
  return acc;
}

// one weight row dotted against two LDS vectors (u_a, u_m share Wr row)
__device__ __forceinline__ void dot2K512(const float* __restrict__ w,
                                         const float* xa, const float* xm,
                                         float& ra, float& rm) {
  int l = threadIdx.x & 63;
  const float4* w4 = (const float4*)w;
  const float4* a4 = (const float4*)xa;
  const float4* m4 = (const float4*)xm;
  float sa = 0.f, sm = 0.f;
  #pragma unroll
  for (int it = 0; it < 2; ++it) {
    float4 wv = w4[l + 64*it], av = a4[l + 64*it], mv = m4[l + 64*it];
    sa += wv.x*av.x + wv.y*av.y + wv.z*av.z + wv.w*av.w;
    sm += wv.x*mv.x + wv.y*mv.y + wv.z*mv.z + wv.w*mv.w;
  }
  #pragma unroll
  for (int o = 32; o; o >>= 1) { sa += __shfl_xor(sa, o, 64); sm += __shfl_xor(sm, o, 64); }
  ra = sa; rm = sm;
}

__device__ __forceinline__ void softmax100_l(const float* g, float* s) {
  int l = threadIdx.x & 63;
  float x1 = g[l];                                    // l < 64 < 100: valid
  float x2 = (l + 64 < 100) ? g[l + 64] : -3.0e38f;
  float m = fmaxf(x1, x2);
  #pragma unroll
  for (int o = 32; o; o >>= 1) m = fmaxf(m, __shfl_xor(m, o, 64));
  float e1 = expf(x1 - m);
  float e2 = (l + 64 < 100) ? expf(x2 - m) : 0.f;
  float ss = e1 + e2;
  #pragma unroll
  for (int o = 32; o; o >>= 1) ss += __shfl_xor(ss, o, 64);
  float inv = 1.f / ss;
  s[l] = e1 * inv;
  if (l + 64 < 100) s[l + 64] = e2 * inv;
}
__device__ __forceinline__ void softmax3_l(const float* g, float* s) {
  int l = threadIdx.x & 63;
  float x = (l < 3) ? g[l] : -3.0e38f;
  float m = x;
  #pragma unroll
  for (int o = 32; o; o >>= 1) m = fmaxf(m, __shfl_xor(m, o, 64));
  float e = (l < 3) ? expf(x - m) : 0.f;
  float ss = e;
  #pragma unroll
  for (int o = 32; o; o >>= 1) ss += __shfl_xor(ss, o, 64);
  if (l < 3) s[l] = e / ss;
}

// ---------------- prep kernels ----------------
__global__ void initK(unsigned long long* carryT, unsigned long long* bcast, float* G) {
  int i = blockIdx.x * blockDim.x + threadIdx.x, st = gridDim.x * blockDim.x;
  for (int k = i; k < 1536; k += st) carryT[k] = (1ull << 32);   // C_0: value 0, tag 1
  for (int k = i; k < 1536; k += st) carryT[1536 + k] = 0ull;
  for (int k = i; k < 2 * 1344; k += st) bcast[k] = 0ull;
  for (int k = i; k < 1536 * 128; k += st) G[k] = 0.f;
}

// dst[C][R] = src[R][C]^T
__global__ void transK(const float* __restrict__ src, float* __restrict__ dst, int R, int C) {
  __shared__ float tile[32][33];
  int c0 = blockIdx.x * 32, r0 = blockIdx.y * 32;
  for (int i = threadIdx.y; i < 32; i += 8) {
    int r = r0 + i, c = c0 + threadIdx.x;
    tile[i][threadIdx.x] = (r < R && c < C) ? src[(size_t)r * C + c] : 0.f;
  }
  __syncthreads();
  for (int i = threadIdx.y; i < 32; i += 8) {
    int c = c0 + i, r = r0 + threadIdx.x;
    if (c < C && r < R) dst[(size_t)c * R + r] = tile[threadIdx.x][i];
  }
}

// C[T,N] = X[T,2048] @ W[2048,N], small-N path (N=100)
__global__ __launch_bounds__(256) void gemmK(const float* __restrict__ X,
                                             const float* __restrict__ W,
                                             float* __restrict__ C, int N) {
  __shared__ float As[16][68];
  __shared__ float Bs[16][68];
  int t0 = blockIdx.y * 64, n0 = blockIdx.x * 64;
  int tid = threadIdx.x, tx = tid & 15, ty = tid >> 4;
  float acc[4][4] = {};
  for (int k0 = 0; k0 < 2048; k0 += 16) {
    {
      int r = tid >> 2, c = (tid & 3) * 4;
      float4 v = *(const float4*)(X + (size_t)(t0 + r) * 2048 + k0 + c);
      As[c + 0][r] = v.x; As[c + 1][r] = v.y; As[c + 2][r] = v.z; As[c + 3][r] = v.w;
    }
    {
      int kr = tid >> 4, c = (tid & 15) * 4;
      int gcol = n0 + c;
      const float* src = W + (size_t)(k0 + kr) * N + gcol;
      #pragma unroll
      for (int i = 0; i < 4; ++i) Bs[kr][c + i] = (gcol + i < N) ? src[i] : 0.f;
    }
    __syncthreads();
    #pragma unroll
    for (int kk = 0; kk < 16; ++kk) {
      float4 a4 = *(const float4*)&As[kk][ty * 4];
      float4 b4 = *(const float4*)&Bs[kk][tx * 4];
      float av[4] = {a4.x, a4.y, a4.z, a4.w};
      float bv[4] = {b4.x, b4.y, b4.z, b4.w};
      #pragma unroll
      for (int i = 0; i < 4; ++i)
        #pragma unroll
        for (int j = 0; j < 4; ++j) acc[i][j] += av[i] * bv[j];
    }
    __syncthreads();
  }
  #pragma unroll
  for (int i = 0; i < 4; ++i)
    #pragma unroll
    for (int j = 0; j < 4; ++j) {
      int col = n0 + tx * 4 + j;
      if (col < N) C[(size_t)(t0 + ty * 4 + i) * N + col] = acc[i][j];
    }
}

// C[T,512] = X[T,2048] @ W[2048,512], 128x128 tile, 8x8 micro
__global__ __launch_bounds__(256) void gemm128(const float* __restrict__ X,
                                               const float* __restrict__ W,
                                               float* __restrict__ C) {
  __shared__ float As[8][132];
  __shared__ float Bs[8][132];
  const int N = 512;
  int t0 = blockIdx.y * 128, n0 = blockIdx.x * 128;
  int tid = threadIdx.x, tx = tid & 15, ty = tid >> 4;
  float acc[8][8] = {};
  for (int k0 = 0; k0 < 2048; k0 += 8) {
    int r = tid >> 1, c4 = (tid & 1) * 4;
    float4 va = *(const float4*)(X + (size_t)(t0 + r) * 2048 + k0 + c4);
    int kr = tid >> 5, cb = (tid & 31) * 4;
    float4 vb = *(const float4*)(W + (size_t)(k0 + kr) * N + n0 + cb);
    __syncthreads();
    As[c4 + 0][r] = va.x; As[c4 + 1][r] = va.y; As[c4 + 2][r] = va.z; As[c4 + 3][r] = va.w;
    Bs[kr][cb] = vb.x; Bs[kr][cb + 1] = vb.y; Bs[kr][cb + 2] = vb.z; Bs[kr][cb + 3] = vb.w;
    __syncthreads();
    #pragma unroll
    for (int kk = 0; kk < 8; ++kk) {
      float av[8], bv[8];
      *(float4*)av       = *(const float4*)&As[kk][ty * 8];
      *(float4*)(av + 4) = *(const float4*)&As[kk][ty * 8 + 4];
      *(float4*)bv       = *(const float4*)&Bs[kk][tx * 8];
      *(float4*)(bv + 4) = *(const float4*)&Bs[kk][tx * 8 + 4];
      #pragma unroll
      for (int i = 0; i < 8; ++i)
        #pragma unroll
        for (int j = 0; j < 8; ++j) acc[i][j] += av[i] * bv[j];
    }
  }
  #pragma unroll
  for (int i = 0; i < 8; ++i) {
    float* dst = C + (size_t)(t0 + ty * 8 + i) * N + n0 + tx * 8;
    *(float4*)dst       = *(float4*)&acc[i][0];
    *(float4*)(dst + 4) = *(float4*)&acc[i][4];
  }
}

// ---------------- persistent recurrence kernel ----------------
struct RArgs {
  const float *TWrp, *TWwp, *TWwpa, *TWwpm, *TWca, *TWcm;
  const float *TWh0, *TWh1, *TWh2, *TWu0, *TWu1, *TWu2;
  const float *PAca, *PMcm, *PArha, *PMrhm, *PAwpa, *PMwpm;
  const float *b_ca, *b_cm, *b_wp, *b_wpa, *b_wpm, *b_rp, *b_rh, *b_rha, *b_rhm;
  float *G;
  unsigned long long *carryT, *bcast;
  float *out;
  int nT;
};

__global__ __launch_bounds__(TPB) void recurK(RArgs a) {
  const int tid  = threadIdx.x;
  const int lane = tid & 63;
  const int lw   = tid >> 6;                 // 0..7
  const int gw   = blockIdx.x * (TPB / 64) + lw;
  const int ownBase = blockIdx.x * OWNB;

  __shared__ __align__(16) float s_x[1536];      // carry staging [ha|hm|h]
  __shared__ __align__(16) float s_bc[1344];     // ca|cm|grp|gwpa|gwpm|gwp
  __shared__ float s_ar[104], s_awa[104], s_awm[104], s_aw[8];
  __shared__ float s_part[OWNB];

  float* s_ca  = s_bc;
  float* s_cm  = s_bc + 512;
  float* s_raw = s_bc + 1024;

  for (int t = 0; t < a.nT; ++t) {
    const unsigned tagA = (unsigned)t + 1;

    // ================= Phase A =================
    // poll carry_t (tagged) into LDS: exactly 3 elems/thread
    {
      const unsigned long long* cin = a.carryT + (size_t)(t & 1) * 1536;
      int i0 = tid, i1 = tid + 512, i2 = tid + 1024;
      unsigned long long v0 = ald(cin + i0), v1 = ald(cin + i1), v2 = ald(cin + i2);
      while (((unsigned)(v0 >> 32) < tagA) | ((unsigned)(v1 >> 32) < tagA) |
             ((unsigned)(v2 >> 32) < tagA)) {
        __builtin_amdgcn_s_sleep(2);
        v0 = ald(cin + i0); v1 = ald(cin + i1); v2 = ald(cin + i2);
      }
      s_x[i0] = __uint_as_float((unsigned)v0);
      s_x[i1] = __uint_as_float((unsigned)v1);
      s_x[i2] = __uint_as_float((unsigned)v2);
    }
    __syncthreads();

    unsigned long long* bc = a.bcast + (size_t)(t & 1) * 1344;

    // distributed jobs → tagged broadcast
    for (int job = gw; job < 1327; job += NWAVE) {
      float v;
      if (job < 512) {                                    // ca
        v = xrsum(dotK<2>(a.TWca + (size_t)job * 512, s_x));
        if (!lane) {
          v = fmaxf(v + a.PAca[(size_t)t * 512 + job] + a.b_ca[job], 0.f);
          gstTag(bc + job, v, tagA);
        }
      } else if (job < 1024) {                            // cm
        int c = job - 512;
        v = xrsum(dotK<2>(a.TWcm + (size_t)c * 512, s_x + 512));
        if (!lane) {
          v = fmaxf(v + a.PMcm[(size_t)t * 512 + c] + a.b_cm[c], 0.f);
          gstTag(bc + job, v, tagA);
        }
      } else if (job < 1124) {                            // grp logits
        int c = job - 1024;
        v = xrsum(dotK<6>(a.TWrp + (size_t)c * 1536, s_x));
        if (!lane) gstTag(bc + job, v + a.b_rp[c], tagA);
      } else if (job < 1224) {                            // gwpa logits
        int c = job - 1124;
        v = xrsum(dotK<2>(a.TWwpa + (size_t)c * 512, s_x));
        if (!lane) gstTag(bc + job, v + a.PAwpa[(size_t)t * 100 + c] + a.b_wpa[c], tagA);
      } else if (job < 1324) {                            // gwpm logits
        int c = job - 1224;
        v = xrsum(dotK<2>(a.TWwpm + (size_t)c * 512, s_x + 512));
        if (!lane) gstTag(bc + job, v + a.PMwpm[(size_t)t * 100 + c] + a.b_wpm[c], tagA);
      } else {                                            // gwp logits (3)
        int c = job - 1324;
        v = xrsum(dotK<6>(a.TWwp + (size_t)c * 1536, s_x));
        if (!lane) gstTag(bc + job, v + a.b_wp[c], tagA);
      }
    }

    // owned partial jobs (block-local, 3 per wave): Wh·carry for our columns
    #pragma unroll
    for (int k = 0; k < 3; ++k) {
      int p = ownBase + lw * 3 + k;
      int head = p >> 9, c = p & 511;
      const float* w  = (head == 0) ? a.TWh0 : (head == 1) ? a.TWh1 : a.TWh2;
      const float* xs = s_x + ((head == 0) ? 1024 : (head == 1) ? 0 : 512);
      float v = xrsum(dotK<2>(w + (size_t)c * 512, xs));
      if (!lane) s_part[lw * 3 + k] = v;
    }

    // ================= Phase B =================
    // poll broadcast (tagged) into LDS
    {
      int i0 = tid, i1 = tid + 512, i2 = tid + 1024;
      bool h2 = (i2 < 1327);
      unsigned long long v0 = ald(bc + i0), v1 = ald(bc + i1);
      unsigned long long v2 = h2 ? ald(bc + i2) : ~0ull;
      while (((unsigned)(v0 >> 32) < tagA) | ((unsigned)(v1 >> 32) < tagA) |
             ((unsigned)(v2 >> 32) < tagA)) {
        __builtin_amdgcn_s_sleep(2);
        v0 = ald(bc + i0); v1 = ald(bc + i1); if (h2) v2 = ald(bc + i2);
      }
      s_bc[i0] = __uint_as_float((unsigned)v0);
      s_bc[i1] = __uint_as_float((unsigned)v1);
      if (h2) s_bc[i2] = __uint_as_float((unsigned)v2);
    }
    __syncthreads();

    // replicated softmaxes (waves 0-3)
    if      (lw == 0) softmax100_l(s_raw,       s_ar);
    else if (lw == 1) softmax100_l(s_raw + 100, s_awa);
    else if (lw == 2) softmax100_l(s_raw + 200, s_awm);
    else if (lw == 3) softmax3_l  (s_raw + 300, s_aw);
    __syncthreads();

    const float aw0 = s_aw[0], aw1 = s_aw[1], aw2 = s_aw[2];
    unsigned long long* cout = a.carryT + (size_t)((t + 1) & 1) * 1536;

    // owned combined jobs: u-dots + contrib + G update + carry'/out write
    #pragma unroll
    for (int k = 0; k < 3; ++k) {
      int q = ownBase + lw * 3 + k;
      int head = q >> 9, j = q & 511;
      const float* wu = (head == 0) ? a.TWu0 : (head == 1) ? a.TWu1 : a.TWu2;
      float uA, uM;
      dot2K512(wu + (size_t)j * 512, s_ca, s_cm, uA, uM);

      float* grow = a.G + (size_t)q * 128;
      int i2 = lane + 64;
      float g1 = grow[lane];
      float g2 = (i2 < 100) ? grow[i2] : 0.f;
      float contrib = s_ar[lane] * g1 + ((i2 < 100) ? s_ar[i2] * g2 : 0.f);
      contrib = xrsum(contrib);
      grow[lane] = aw0 * g1 + aw1 * s_awa[lane] * uA + aw2 * s_awm[lane] * uM;
      if (i2 < 100)
        grow[i2] = aw0 * g2 + aw1 * s_awa[i2] * uA + aw2 * s_awm[i2] * uM;

      if (!lane) {
        float base = s_part[lw * 3 + k];
        if (head == 0) {
          float v = fmaxf(contrib + base + a.b_rh[j], 0.f);
          a.out[(size_t)t * 512 + j] = v;
          gstTag(cout + 1024 + j, v, tagA + 1);
        } else if (head == 1) {
          float v = fmaxf(contrib + base + a.PArha[(size_t)t * 512 + j] + a.b_rha[j], 0.f);
          gstTag(cout + j, v, tagA + 1);
        } else {
          float v = fmaxf(contrib + base + a.PMrhm[(size_t)t * 512 + j] + a.b_rhm[j], 0.f);
          gstTag(cout + 512 + j, v, tagA + 1);
        }
      }
    }
    __syncthreads();   // protect s_bc / s_ar from next step's staging
  }
}

// ---------------- host ----------------
extern "C" void kernel_launch(void* const* d_in, const int* in_sizes, int n_in,
                              void* d_out, int out_size, void* d_ws, size_t ws_size,
                              hipStream_t stream) {
  const float* Xa    = (const float*)d_in[0];
  const float* Xm    = (const float*)d_in[1];
  const float* W_ca  = (const float*)d_in[2];  const float* b_ca  = (const float*)d_in[3];
  const float* W_cm  = (const float*)d_in[4];  const float* b_cm  = (const float*)d_in[5];
  const float* W_wp  = (const float*)d_in[6];  const float* b_wp  = (const float*)d_in[7];
  const float* W_wpa = (const float*)d_in[8];  const float* b_wpa = (const float*)d_in[9];
  const float* W_wpm = (const float*)d_in[10]; const float* b_wpm = (const float*)d_in[11];
  const float* W_rp  = (const float*)d_in[12]; const float* b_rp  = (const float*)d_in[13];
  const float* W_rh  = (const float*)d_in[14]; const float* b_rh  = (const float*)d_in[15];
  const float* W_rha = (const float*)d_in[16]; const float* b_rha = (const float*)d_in[17];
  const float* W_rhm = (const float*)d_in[18]; const float* b_rhm = (const float*)d_in[19];

  int nT = out_size / HS;   // 4096
  float* ws = (float*)d_ws;

  initK<<<dim3(256), dim3(256), 0, stream>>>(
      (unsigned long long*)(ws + OFF_CARRY),
      (unsigned long long*)(ws + OFF_BCAST),
      ws + OFF_G);

  dim3 tb(32, 8);
  auto tg = [](int R, int C) { return dim3((C + 31) / 32, (R + 31) / 32); };
  transK<<<tg(1536, 100), tb, 0, stream>>>(W_rp,              ws + OFF_TWrp,  1536, 100);
  transK<<<tg(1536, 3),   tb, 0, stream>>>(W_wp,              ws + OFF_TWwp,  1536, 3);
  transK<<<tg(512, 100),  tb, 0, stream>>>(W_wpa,             ws + OFF_TWwpa, 512, 100);
  transK<<<tg(512, 100),  tb, 0, stream>>>(W_wpm,             ws + OFF_TWwpm, 512, 100);
  transK<<<tg(512, 512),  tb, 0, stream>>>(W_ca,              ws + OFF_TWca,  512, 512);
  transK<<<tg(512, 512),  tb, 0, stream>>>(W_cm,              ws + OFF_TWcm,  512, 512);
  transK<<<tg(512, 512),  tb, 0, stream>>>(W_rh  + 512 * 512, ws + OFF_TWh0,  512, 512);
  transK<<<tg(512, 512),  tb, 0, stream>>>(W_rha + (size_t)2560 * 512, ws + OFF_TWh1, 512, 512);
  transK<<<tg(512, 512),  tb, 0, stream>>>(W_rhm + (size_t)2560 * 512, ws + OFF_TWh2, 512, 512);
  transK<<<tg(512, 512),  tb, 0, stream>>>(W_rh,              ws + OFF_TWu0,  512, 512);
  transK<<<tg(512, 512),  tb, 0, stream>>>(W_rha + (size_t)2048 * 512, ws + OFF_TWu1, 512, 512);
  transK<<<tg(512, 512),  tb, 0, stream>>>(W_rhm + (size_t)2048 * 512, ws + OFF_TWu2, 512, 512);

  int tB = nT / 128;
  gemm128<<<dim3(4, tB), dim3(256), 0, stream>>>(Xa, W_ca + (size_t)512 * 512, ws + OFF_PAca);
  gemm128<<<dim3(4, tB), dim3(256), 0, stream>>>(Xm, W_cm + (size_t)512 * 512, ws + OFF_PMcm);
  gemm128<<<dim3(4, tB), dim3(256), 0, stream>>>(Xa, W_rha,                    ws + OFF_PArha);
  gemm128<<<dim3(4, tB), dim3(256), 0, stream>>>(Xm, W_rhm,                    ws + OFF_PMrhm);
  int tB64 = nT / 64;
  gemmK<<<dim3(2, tB64), dim3(256), 0, stream>>>(Xa, W_wpa + (size_t)512 * 100, ws + OFF_PAwpa, 100);
  gemmK<<<dim3(2, tB64), dim3(256), 0, stream>>>(Xm, W_wpm + (size_t)512 * 100, ws + OFF_PMwpm, 100);

  RArgs a;
  a.TWrp  = ws + OFF_TWrp;  a.TWwp  = ws + OFF_TWwp;
  a.TWwpa = ws + OFF_TWwpa; a.TWwpm = ws + OFF_TWwpm;
  a.TWca  = ws + OFF_TWca;  a.TWcm  = ws + OFF_TWcm;
  a.TWh0  = ws + OFF_TWh0;  a.TWh1  = ws + OFF_TWh1;  a.TWh2 = ws + OFF_TWh2;
  a.TWu0  = ws + OFF_TWu0;  a.TWu1  = ws + OFF_TWu1;  a.TWu2 = ws + OFF_TWu2;
  a.PAca  = ws + OFF_PAca;  a.PMcm  = ws + OFF_PMcm;
  a.PArha = ws + OFF_PArha; a.PMrhm = ws + OFF_PMrhm;
  a.PAwpa = ws + OFF_PAwpa; a.PMwpm = ws + OFF_PMwpm;
  a.b_ca = b_ca; a.b_cm = b_cm; a.b_wp = b_wp; a.b_wpa = b_wpa; a.b_wpm = b_wpm;
  a.b_rp = b_rp; a.b_rh = b_rh; a.b_rha = b_rha; a.b_rhm = b_rhm;
  a.G      = ws + OFF_G;
  a.carryT = (unsigned long long*)(ws + OFF_CARRY);
  a.bcast  = (unsigned long long*)(ws + OFF_BCAST);
  a.out    = (float*)d_out;
  a.nT     = nT;

  recurK<<<dim3(GBLK), dim3(TPB), 0, stream>>>(a);
}